// Round 13
// baseline (80.046 us; speedup 1.0000x reference)
//
#include <hip/hip_runtime.h>

#define BATCH 128
#define LEN 512
#define NCHUNK 8
#define CH_STEPS 64           // chunks 0-6: 64 steps; chunk 7: 63
#define STEPS_TOTAL 511
#define SIG_DIM 4680          // 8 + 64 + 512 + 4096
#define N_OUT 10
#define OFF2 8
#define OFF3 72
#define OFF4 584

typedef float v4f __attribute__((ext_vector_type(4)));

// select channel n (0..7) from the v4f pair; 7 v_cndmask w/ SGPR masks.
__device__ __forceinline__ float sel8(v4f a, v4f b, int n) {
    const float lo = (n & 2) ? ((n & 1) ? a.w : a.z) : ((n & 1) ? a.y : a.x);
    const float hi = (n & 2) ? ((n & 1) ? b.w : b.z) : ((n & 1) ? b.y : b.x);
    return (n & 4) ? hi : lo;
}

// ---------------------------------------------------------------------------
// Phase A (wave 0 only; lane l = i*8+j): the sequential s1/s2 scan. Emits
// per-step (w,u) coefficients to LDS; also stores final s1, s2 (levels 1-2).
// Computed ONCE per (i,j) instead of 8x-redundantly per thread.
// ---------------------------------------------------------------------------
template <int NST>
__device__ __forceinline__ void phaseA(const v4f* __restrict__ Xv, int s0,
                                       float2* __restrict__ wu,
                                       float* __restrict__ o, int l) {
    const int i = l >> 3, j = l & 7;
    float s1 = 0.f, s2 = 0.f;
    v4f pA = Xv[s0 * 2], pB = Xv[s0 * 2 + 1];
    const v4f* __restrict__ Xn = Xv + (s0 + 1) * 2;
    #pragma unroll 4
    for (int s = 0; s < NST; ++s) {
        const v4f cA = Xn[s * 2], cB = Xn[s * 2 + 1];   // uniform VMEM
        const v4f dA = cA - pA, dB = cB - pB;
        pA = cA; pB = cB;
        const float vi = sel8(dA, dB, i);
        const float vj = sel8(dA, dB, j);
        const float t1 = s1 * vj;
        const float p  = vi * vj;
        // u = s2/2 + t1/6 + p/24 ; w = s2 + t1/2 + p/6   (pre-step state)
        const float u = fmaf(1.f / 24.f, p, fmaf(1.f / 6.f, t1, 0.5f * s2));
        const float w = fmaf(1.f / 6.f, p, fmaf(0.5f, t1, s2));
        wu[s * 64 + l] = make_float2(w, u);
        s2 = fmaf(0.5f, p, s2 + t1);
        s1 += vi;
    }
    if ((l & 7) == 0) o[l >> 3] = s1;      // s1[i]
    o[OFF2 + l] = s2;                      // s2[i*8+j]
}

// ---------------------------------------------------------------------------
// Phase B (all 512 threads; t -> (ij = t>>3, k = t&7)): dependence-free
// accumulation  s4[l] = sum_s a(s)*R(s,l) + b(s)*dx(s,l),  s3 = sum_s a(s),
// with a = w*dx_k, b = u*dx_k and R(s) the strict suffix sum of dx
// (telescoped: R -= dx each step; init = X[s0+NST] - X[s0]).
// ---------------------------------------------------------------------------
template <int NST>
__device__ __forceinline__ void phaseB(const v4f* __restrict__ Xv, int s0,
                                       const float2* __restrict__ wu,
                                       float* __restrict__ o, int t) {
    const int ij = t >> 3, k = t & 7;
    float s3 = 0.f;
    v4f s4a = {0.f, 0.f, 0.f, 0.f};
    v4f s4b = {0.f, 0.f, 0.f, 0.f};
    v4f pA = Xv[s0 * 2], pB = Xv[s0 * 2 + 1];
    v4f RA = Xv[(s0 + NST) * 2]     - pA;   // sum of all chunk dx
    v4f RB = Xv[(s0 + NST) * 2 + 1] - pB;
    const v4f* __restrict__ Xn = Xv + (s0 + 1) * 2;

    #pragma unroll 4
    for (int s = 0; s < NST; ++s) {
        const v4f cA = Xn[s * 2], cB = Xn[s * 2 + 1];   // uniform VMEM
        const v4f dA = cA - pA, dB = cB - pB;
        pA = cA; pB = cB;
        RA -= dA; RB -= dB;                 // strict suffix R(s)

        const float2 wuv = wu[s * 64 + ij]; // ds_read_b64 broadcast
        const float dxk = sel8(dA, dB, k);
        const float a  = wuv.x * dxk;
        const float bb = wuv.y * dxk;
        const v4f av = {a, a, a, a};
        const v4f bv = {bb, bb, bb, bb};
        s4a = __builtin_elementwise_fma(av, RA, s4a);
        s4a = __builtin_elementwise_fma(bv, dA, s4a);
        s4b = __builtin_elementwise_fma(av, RB, s4b);
        s4b = __builtin_elementwise_fma(bv, dB, s4b);
        s3 += a;
    }

    o[OFF3 + t] = s3;
    *(v4f*)&o[OFF4 + t * 8]     = s4a;
    *(v4f*)&o[OFF4 + t * 8 + 4] = s4b;
}

// ---------------------------------------------------------------------------
// Kernel 1: per-(batch, eighth) depth-4 signature, phase-split Chen scan.
// 1024 blocks x 512 threads = 4 blocks/CU. LDS = 32 KB (w,u table).
// ---------------------------------------------------------------------------
__global__ __launch_bounds__(512) void sig_chunk_kernel(const float* __restrict__ X,
                                                        float* __restrict__ sig) {
    const int wg = blockIdx.x;          // b * 8 + ch
    const int b  = wg >> 3;
    const int ch = wg & 7;
    const int s0 = ch * CH_STEPS;
    const int t = threadIdx.x;

    __shared__ __align__(16) float2 wu[CH_STEPS * 64];   // 32 KB: [s][ij]

    const v4f* __restrict__ Xv = (const v4f*)(X + (size_t)b * LEN * 8);
    float* __restrict__ o = sig + (size_t)wg * SIG_DIM;

    if (t < 64) {
        if (ch != 7) phaseA<CH_STEPS>(Xv, s0, wu, o, t);
        else         phaseA<CH_STEPS - 1>(Xv, s0, wu, o, t);
    }
    __syncthreads();

    if (ch != 7) phaseB<CH_STEPS>(Xv, s0, wu, o, t);
    else         phaseB<CH_STEPS - 1>(Xv, s0, wu, o, t);
}

// ---------------------------------------------------------------------------
// Chen combine: (A own-components in registers) ∘= (B cross-components via
// pointer -- global or LDS; addrspace resolved after inlining).
// ---------------------------------------------------------------------------
__device__ __forceinline__ void chen_combine(float& A1, float& A2, float& A3,
                                             float A4[8],
                                             const float* __restrict__ B,
                                             int i, int j, int k, int t) {
    const float B1i = B[i], B1j = B[j], B1k = B[k];
    const float4 b1a = *(const float4*)&B[0];
    const float4 b1b = *(const float4*)&B[4];
    const float B2ij = B[OFF2 + i * 8 + j];
    const float B2jk = B[OFF2 + j * 8 + k];
    const float4 b2a = *(const float4*)&B[OFF2 + k * 8];
    const float4 b2b = *(const float4*)&B[OFF2 + k * 8 + 4];
    const float B3ijk = B[OFF3 + t];
    const float4 b3a = *(const float4*)&B[OFF3 + (j * 8 + k) * 8];
    const float4 b3b = *(const float4*)&B[OFF3 + (j * 8 + k) * 8 + 4];
    const float4 b4a = *(const float4*)&B[OFF4 + t * 8];
    const float4 b4b = *(const float4*)&B[OFF4 + t * 8 + 4];

    // C4 = A4 + A3⊗B1 + A2⊗B2 + A1⊗B3 + B4   (old A1..A3)
    A4[0] += A3 * b1a.x + A2 * b2a.x + A1 * b3a.x + b4a.x;
    A4[1] += A3 * b1a.y + A2 * b2a.y + A1 * b3a.y + b4a.y;
    A4[2] += A3 * b1a.z + A2 * b2a.z + A1 * b3a.z + b4a.z;
    A4[3] += A3 * b1a.w + A2 * b2a.w + A1 * b3a.w + b4a.w;
    A4[4] += A3 * b1b.x + A2 * b2b.x + A1 * b3b.x + b4b.x;
    A4[5] += A3 * b1b.y + A2 * b2b.y + A1 * b3b.y + b4b.y;
    A4[6] += A3 * b1b.z + A2 * b2b.z + A1 * b3b.z + b4b.z;
    A4[7] += A3 * b1b.w + A2 * b2b.w + A1 * b3b.w + b4b.w;
    // C3 = A3 + A2⊗B1 + A1⊗B2 + B3
    A3 += A2 * B1k + A1 * B2jk + B3ijk;
    // C2 = A2 + A1⊗B1 + B2
    A2 += A1 * B1j + B2ij;
    // C1
    A1 += B1i;
}

__device__ __forceinline__ void load_own(const float* __restrict__ S,
                                         float& A1, float& A2, float& A3,
                                         float A4[8], int i, int j, int t) {
    A1 = S[i];
    A2 = S[OFF2 + i * 8 + j];
    A3 = S[OFF3 + t];
    const float4 a = *(const float4*)&S[OFF4 + t * 8];
    const float4 b = *(const float4*)&S[OFF4 + t * 8 + 4];
    A4[0] = a.x; A4[1] = a.y; A4[2] = a.z; A4[3] = a.w;
    A4[4] = b.x; A4[5] = b.y; A4[6] = b.z; A4[7] = b.w;
}

__device__ __forceinline__ void stage_lds(float* __restrict__ Bs,
                                          float A1, float A2, float A3,
                                          const float A4[8], int t) {
    if ((t & 63) == 0) Bs[t >> 6] = A1;
    if ((t & 7) == 0)  Bs[OFF2 + (t >> 3)] = A2;
    Bs[OFF3 + t] = A3;
    *(float4*)&Bs[OFF4 + t * 8]     = make_float4(A4[0], A4[1], A4[2], A4[3]);
    *(float4*)&Bs[OFF4 + t * 8 + 4] = make_float4(A4[4], A4[5], A4[6], A4[7]);
}

// ---------------------------------------------------------------------------
// Kernel 2 (verified R10/R12): 3-level pairwise Chen-combine tree over 8
// chunk signatures + fused linear + block reduction. 128 blocks x 512 thr.
// ---------------------------------------------------------------------------
__global__ __launch_bounds__(512) void sig_combine_linear(const float* __restrict__ sig,
                                                          const float* __restrict__ W,
                                                          const float* __restrict__ bias,
                                                          float* __restrict__ out) {
    const int b = blockIdx.x;
    const int t = threadIdx.x;
    const int i = t >> 6, j = (t >> 3) & 7, k = t & 7;
    const float* __restrict__ S = sig + (size_t)b * NCHUNK * SIG_DIM;

    __shared__ __align__(16) float Bs0[SIG_DIM];
    __shared__ __align__(16) float Bs1[SIG_DIM];

    // level 1 (all from global, L2-resident):
    {
        float C1, C2, C3, C4[8];
        load_own(S + 2 * SIG_DIM, C1, C2, C3, C4, i, j, t);
        chen_combine(C1, C2, C3, C4, S + 3 * SIG_DIM, i, j, k, t);
        stage_lds(Bs0, C1, C2, C3, C4, t);
    }
    {
        float C1, C2, C3, C4[8];
        load_own(S + 6 * SIG_DIM, C1, C2, C3, C4, i, j, t);
        chen_combine(C1, C2, C3, C4, S + 7 * SIG_DIM, i, j, k, t);
        stage_lds(Bs1, C1, C2, C3, C4, t);
    }

    // C01 (running accumulator A in registers)
    float A1, A2, A3, A4[8];
    load_own(S, A1, A2, A3, A4, i, j, t);
    chen_combine(A1, A2, A3, A4, S + SIG_DIM, i, j, k, t);

    // C45 (registers)
    float D1, D2, D3, D4[8];
    load_own(S + 4 * SIG_DIM, D1, D2, D3, D4, i, j, t);
    chen_combine(D1, D2, D3, D4, S + 5 * SIG_DIM, i, j, k, t);

    __syncthreads();                      // LDS0 = C23, LDS1 = C67 ready

    // level 2: A = C0123, D = C4567
    chen_combine(A1, A2, A3, A4, Bs0, i, j, k, t);
    chen_combine(D1, D2, D3, D4, Bs1, i, j, k, t);

    __syncthreads();                      // everyone done reading LDS0
    stage_lds(Bs0, D1, D2, D3, D4, t);
    __syncthreads();                      // LDS0 = C4567 ready

    // level 3: A = full signature
    chen_combine(A1, A2, A3, A4, Bs0, i, j, k, t);

    // Fused linear: out[b][n] = sum_d sig[d] * W[n][d] + bias[n]
    float part[N_OUT];
    #pragma unroll
    for (int n = 0; n < N_OUT; ++n) {
        const float* __restrict__ Wn = W + (size_t)n * SIG_DIM;
        float p = A3 * Wn[OFF3 + t];
        const float4 w4a = *(const float4*)&Wn[OFF4 + t * 8];
        const float4 w4b = *(const float4*)&Wn[OFF4 + t * 8 + 4];
        p = fmaf(A4[0], w4a.x, p);
        p = fmaf(A4[1], w4a.y, p);
        p = fmaf(A4[2], w4a.z, p);
        p = fmaf(A4[3], w4a.w, p);
        p = fmaf(A4[4], w4b.x, p);
        p = fmaf(A4[5], w4b.y, p);
        p = fmaf(A4[6], w4b.z, p);
        p = fmaf(A4[7], w4b.w, p);
        if ((t & 7) == 0)  p = fmaf(A2, Wn[OFF2 + (t >> 3)], p);  // canonical s2 owner
        if ((t & 63) == 0) p = fmaf(A1, Wn[t >> 6], p);           // canonical s1 owner
        part[n] = p;
    }

    // wave reduce (64 lanes) then cross-wave via LDS
    #pragma unroll
    for (int n = 0; n < N_OUT; ++n) {
        #pragma unroll
        for (int off = 32; off > 0; off >>= 1)
            part[n] += __shfl_xor(part[n], off, 64);
    }
    __shared__ float red[8][N_OUT];
    const int wv = t >> 6, ln = t & 63;
    if (ln == 0) {
        #pragma unroll
        for (int n = 0; n < N_OUT; ++n) red[wv][n] = part[n];
    }
    __syncthreads();
    if (t < N_OUT) {
        float s = bias[t];
        #pragma unroll
        for (int w = 0; w < 8; ++w) s += red[w][t];
        out[b * N_OUT + t] = s;
    }
}

extern "C" void kernel_launch(void* const* d_in, const int* in_sizes, int n_in,
                              void* d_out, int out_size, void* d_ws, size_t ws_size,
                              hipStream_t stream) {
    const float* X    = (const float*)d_in[0];
    const float* W    = (const float*)d_in[1];
    const float* bias = (const float*)d_in[2];
    float* out = (float*)d_out;
    float* sig = (float*)d_ws;                 // NCHUNK*BATCH*SIG_DIM*4 ≈ 19.2 MB

    hipLaunchKernelGGL(sig_chunk_kernel, dim3(BATCH * NCHUNK), dim3(512), 0, stream, X, sig);
    hipLaunchKernelGGL(sig_combine_linear, dim3(BATCH), dim3(512), 0, stream, sig, W, bias, out);
}

// Round 14
// 47.693 us; speedup vs baseline: 1.6784x; 1.6784x over previous
//
#include <hip/hip_runtime.h>

#define BATCH 128
#define LEN 512
#define NCHUNK 8
#define CH_STEPS 64           // chunks 0-6: 64 steps; chunk 7: 63 (runtime bound)
#define STEPS_TOTAL 511
#define SIG_DIM 4680          // 8 + 64 + 512 + 4096
#define N_OUT 10
#define OFF2 8
#define OFF3 72
#define OFF4 584

typedef float v4f __attribute__((ext_vector_type(4)));

// ---------------------------------------------------------------------------
// Per-wave scan body. WV = wave index (compile-time) = owned i. nst runtime
// (64 or 63). Lean step (R9/R10 structure) + EXPLICIT 1-deep software
// pipeline: iteration s issues the loads for s+1 (nA,nB via uniform VMEM;
// vjn,vkn via LDS broadcast) before consuming the already-resident cA,cB,
// vjc,vkc. Named prefetch variables force live ranges across the compute
// block -> compiler must hold them in VGPRs and hoist the loads.
// ---------------------------------------------------------------------------
template <int WV>
__device__ __forceinline__ void scan_body(const v4f* __restrict__ Xv, int s0,
                                          int nst, const float* __restrict__ dxs,
                                          float* __restrict__ o, int t) {
    const int j = (t >> 3) & 7, k = t & 7;
    float s1v = 0.f, s2v = 0.f, s3v = 0.f;
    float s4[8] = {0.f, 0.f, 0.f, 0.f, 0.f, 0.f, 0.f, 0.f};

    v4f pA = Xv[s0 * 2], pB = Xv[s0 * 2 + 1];
    const v4f* __restrict__ Xn = Xv + (s0 + 1) * 2;

    // preload iteration 0 into the pipeline registers
    v4f cA = Xn[0], cB = Xn[1];
    float vjc = dxs[j], vkc = dxs[k];

    #pragma unroll 4
    for (int s = 0; s < nst; ++s) {
        // ---- issue next iteration's loads FIRST (sp clamped, always valid)
        const int sp = min(s + 1, nst - 1);
        const v4f nA = Xn[sp * 2];                 // uniform VMEM dwordx4
        const v4f nB = Xn[sp * 2 + 1];
        const float vjn = dxs[sp * 8 + j];         // LDS broadcast
        const float vkn = dxs[sp * 8 + k];         // LDS broadcast

        // ---- compute iteration s from resident registers
        const v4f dA = cA - pA;
        const v4f dB = cB - pB;
        pA = cA; pB = cB;
        const float vi = (WV < 4) ? dA[WV & 3] : dB[WV & 3];  // free extract

        const float t1 = s1v * vjc;
        const float p  = vi * vjc;
        // u = s2/2 + t1/6 + p/24 ; w = s2 + t1/2 + p/6   (pre-step state)
        const float u  = fmaf(1.f / 24.f, p, fmaf(1.f / 6.f, t1, 0.5f * s2v));
        const float w  = fmaf(1.f / 6.f, p, fmaf(0.5f, t1, s2v));
        const float cc = fmaf(vkc, u, s3v);        // level-4 coefficient
        s4[0] = fmaf(cc, dA.x, s4[0]);
        s4[1] = fmaf(cc, dA.y, s4[1]);
        s4[2] = fmaf(cc, dA.z, s4[2]);
        s4[3] = fmaf(cc, dA.w, s4[3]);
        s4[4] = fmaf(cc, dB.x, s4[4]);
        s4[5] = fmaf(cc, dB.y, s4[5]);
        s4[6] = fmaf(cc, dB.z, s4[6]);
        s4[7] = fmaf(cc, dB.w, s4[7]);
        s3v = fmaf(vkc, w, s3v);
        s2v = fmaf(0.5f, p, s2v + t1);
        s1v += vi;

        // ---- rotate the pipeline
        cA = nA; cB = nB; vjc = vjn; vkc = vkn;
    }

    if ((t & 63) == 0) o[WV] = s1v;                    // s1[i], i == WV
    if ((t & 7) == 0)  o[OFF2 + (t >> 3)] = s2v;       // s2[ij]
    o[OFF3 + t] = s3v;
    *(float4*)&o[OFF4 + t * 8]     = make_float4(s4[0], s4[1], s4[2], s4[3]);
    *(float4*)&o[OFF4 + t * 8 + 4] = make_float4(s4[4], s4[5], s4[6], s4[7]);
}

// ---------------------------------------------------------------------------
// Kernel 1: per-(batch, eighth) depth-4 signature via Chen scan.
// Thread t owns (i,j,k) = (t>>6, (t>>3)&7, t&7); i == wave id.
// 1024 blocks x 512 threads = 4 blocks/CU (up to 8 waves/SIMD).
// ---------------------------------------------------------------------------
__global__ __launch_bounds__(512) void sig_chunk_kernel(const float* __restrict__ X,
                                                        float* __restrict__ sig) {
    const int wg = blockIdx.x;          // b * 8 + ch
    const int b  = wg >> 3;
    const int ch = wg & 7;
    const int s0 = ch * CH_STEPS;
    const int nst = (ch == 7) ? (STEPS_TOTAL - 7 * CH_STEPS) : CH_STEPS;  // 63 : 64
    const int t = threadIdx.x;

    __shared__ __align__(8) float dxs[CH_STEPS * 8];   // 2 KB, for vj/vk reads
    if (t < CH_STEPS * 4) {                            // 256 float2 slots
        const float2* __restrict__ Xg2 =
            (const float2*)(X + ((size_t)b * LEN + s0) * 8);
        float2 r = make_float2(0.f, 0.f);
        if ((t >> 2) < nst) {                          // guard chunk-7 pad row
            const float2 a = Xg2[t], c = Xg2[t + 4];
            r = make_float2(c.x - a.x, c.y - a.y);
        }
        ((float2*)dxs)[t] = r;
    }
    __syncthreads();

    const v4f* __restrict__ Xv = (const v4f*)(X + (size_t)b * LEN * 8);
    float* __restrict__ o = sig + (size_t)wg * SIG_DIM;
    switch (t >> 6) {
        case 0: scan_body<0>(Xv, s0, nst, dxs, o, t); break;
        case 1: scan_body<1>(Xv, s0, nst, dxs, o, t); break;
        case 2: scan_body<2>(Xv, s0, nst, dxs, o, t); break;
        case 3: scan_body<3>(Xv, s0, nst, dxs, o, t); break;
        case 4: scan_body<4>(Xv, s0, nst, dxs, o, t); break;
        case 5: scan_body<5>(Xv, s0, nst, dxs, o, t); break;
        case 6: scan_body<6>(Xv, s0, nst, dxs, o, t); break;
        default: scan_body<7>(Xv, s0, nst, dxs, o, t); break;
    }
}

// ---------------------------------------------------------------------------
// Chen combine: (A own-components in registers) ∘= (B cross-components via
// pointer -- global or LDS; addrspace resolved after inlining).
// ---------------------------------------------------------------------------
__device__ __forceinline__ void chen_combine(float& A1, float& A2, float& A3,
                                             float A4[8],
                                             const float* __restrict__ B,
                                             int i, int j, int k, int t) {
    const float B1i = B[i], B1j = B[j], B1k = B[k];
    const float4 b1a = *(const float4*)&B[0];
    const float4 b1b = *(const float4*)&B[4];
    const float B2ij = B[OFF2 + i * 8 + j];
    const float B2jk = B[OFF2 + j * 8 + k];
    const float4 b2a = *(const float4*)&B[OFF2 + k * 8];
    const float4 b2b = *(const float4*)&B[OFF2 + k * 8 + 4];
    const float B3ijk = B[OFF3 + t];
    const float4 b3a = *(const float4*)&B[OFF3 + (j * 8 + k) * 8];
    const float4 b3b = *(const float4*)&B[OFF3 + (j * 8 + k) * 8 + 4];
    const float4 b4a = *(const float4*)&B[OFF4 + t * 8];
    const float4 b4b = *(const float4*)&B[OFF4 + t * 8 + 4];

    // C4 = A4 + A3⊗B1 + A2⊗B2 + A1⊗B3 + B4   (old A1..A3)
    A4[0] += A3 * b1a.x + A2 * b2a.x + A1 * b3a.x + b4a.x;
    A4[1] += A3 * b1a.y + A2 * b2a.y + A1 * b3a.y + b4a.y;
    A4[2] += A3 * b1a.z + A2 * b2a.z + A1 * b3a.z + b4a.z;
    A4[3] += A3 * b1a.w + A2 * b2a.w + A1 * b3a.w + b4a.w;
    A4[4] += A3 * b1b.x + A2 * b2b.x + A1 * b3b.x + b4b.x;
    A4[5] += A3 * b1b.y + A2 * b2b.y + A1 * b3b.y + b4b.y;
    A4[6] += A3 * b1b.z + A2 * b2b.z + A1 * b3b.z + b4b.z;
    A4[7] += A3 * b1b.w + A2 * b2b.w + A1 * b3b.w + b4b.w;
    // C3 = A3 + A2⊗B1 + A1⊗B2 + B3
    A3 += A2 * B1k + A1 * B2jk + B3ijk;
    // C2 = A2 + A1⊗B1 + B2
    A2 += A1 * B1j + B2ij;
    // C1
    A1 += B1i;
}

__device__ __forceinline__ void load_own(const float* __restrict__ S,
                                         float& A1, float& A2, float& A3,
                                         float A4[8], int i, int j, int t) {
    A1 = S[i];
    A2 = S[OFF2 + i * 8 + j];
    A3 = S[OFF3 + t];
    const float4 a = *(const float4*)&S[OFF4 + t * 8];
    const float4 b = *(const float4*)&S[OFF4 + t * 8 + 4];
    A4[0] = a.x; A4[1] = a.y; A4[2] = a.z; A4[3] = a.w;
    A4[4] = b.x; A4[5] = b.y; A4[6] = b.z; A4[7] = b.w;
}

__device__ __forceinline__ void stage_lds(float* __restrict__ Bs,
                                          float A1, float A2, float A3,
                                          const float A4[8], int t) {
    if ((t & 63) == 0) Bs[t >> 6] = A1;
    if ((t & 7) == 0)  Bs[OFF2 + (t >> 3)] = A2;
    Bs[OFF3 + t] = A3;
    *(float4*)&Bs[OFF4 + t * 8]     = make_float4(A4[0], A4[1], A4[2], A4[3]);
    *(float4*)&Bs[OFF4 + t * 8 + 4] = make_float4(A4[4], A4[5], A4[6], A4[7]);
}

// ---------------------------------------------------------------------------
// Kernel 2 (verified R10/R12): 3-level pairwise Chen-combine tree over 8
// chunk signatures + fused linear + block reduction. 128 blocks x 512 thr.
// ---------------------------------------------------------------------------
__global__ __launch_bounds__(512) void sig_combine_linear(const float* __restrict__ sig,
                                                          const float* __restrict__ W,
                                                          const float* __restrict__ bias,
                                                          float* __restrict__ out) {
    const int b = blockIdx.x;
    const int t = threadIdx.x;
    const int i = t >> 6, j = (t >> 3) & 7, k = t & 7;
    const float* __restrict__ S = sig + (size_t)b * NCHUNK * SIG_DIM;

    __shared__ __align__(16) float Bs0[SIG_DIM];
    __shared__ __align__(16) float Bs1[SIG_DIM];

    // level 1 (all from global, L2-resident):
    {
        float C1, C2, C3, C4[8];
        load_own(S + 2 * SIG_DIM, C1, C2, C3, C4, i, j, t);
        chen_combine(C1, C2, C3, C4, S + 3 * SIG_DIM, i, j, k, t);
        stage_lds(Bs0, C1, C2, C3, C4, t);
    }
    {
        float C1, C2, C3, C4[8];
        load_own(S + 6 * SIG_DIM, C1, C2, C3, C4, i, j, t);
        chen_combine(C1, C2, C3, C4, S + 7 * SIG_DIM, i, j, k, t);
        stage_lds(Bs1, C1, C2, C3, C4, t);
    }

    // C01 (running accumulator A in registers)
    float A1, A2, A3, A4[8];
    load_own(S, A1, A2, A3, A4, i, j, t);
    chen_combine(A1, A2, A3, A4, S + SIG_DIM, i, j, k, t);

    // C45 (registers)
    float D1, D2, D3, D4[8];
    load_own(S + 4 * SIG_DIM, D1, D2, D3, D4, i, j, t);
    chen_combine(D1, D2, D3, D4, S + 5 * SIG_DIM, i, j, k, t);

    __syncthreads();                      // LDS0 = C23, LDS1 = C67 ready

    // level 2: A = C0123, D = C4567
    chen_combine(A1, A2, A3, A4, Bs0, i, j, k, t);
    chen_combine(D1, D2, D3, D4, Bs1, i, j, k, t);

    __syncthreads();                      // everyone done reading LDS0
    stage_lds(Bs0, D1, D2, D3, D4, t);
    __syncthreads();                      // LDS0 = C4567 ready

    // level 3: A = full signature
    chen_combine(A1, A2, A3, A4, Bs0, i, j, k, t);

    // Fused linear: out[b][n] = sum_d sig[d] * W[n][d] + bias[n]
    float part[N_OUT];
    #pragma unroll
    for (int n = 0; n < N_OUT; ++n) {
        const float* __restrict__ Wn = W + (size_t)n * SIG_DIM;
        float p = A3 * Wn[OFF3 + t];
        const float4 w4a = *(const float4*)&Wn[OFF4 + t * 8];
        const float4 w4b = *(const float4*)&Wn[OFF4 + t * 8 + 4];
        p = fmaf(A4[0], w4a.x, p);
        p = fmaf(A4[1], w4a.y, p);
        p = fmaf(A4[2], w4a.z, p);
        p = fmaf(A4[3], w4a.w, p);
        p = fmaf(A4[4], w4b.x, p);
        p = fmaf(A4[5], w4b.y, p);
        p = fmaf(A4[6], w4b.z, p);
        p = fmaf(A4[7], w4b.w, p);
        if ((t & 7) == 0)  p = fmaf(A2, Wn[OFF2 + (t >> 3)], p);  // canonical s2 owner
        if ((t & 63) == 0) p = fmaf(A1, Wn[t >> 6], p);           // canonical s1 owner
        part[n] = p;
    }

    // wave reduce (64 lanes) then cross-wave via LDS
    #pragma unroll
    for (int n = 0; n < N_OUT; ++n) {
        #pragma unroll
        for (int off = 32; off > 0; off >>= 1)
            part[n] += __shfl_xor(part[n], off, 64);
    }
    __shared__ float red[8][N_OUT];
    const int wv = t >> 6, ln = t & 63;
    if (ln == 0) {
        #pragma unroll
        for (int n = 0; n < N_OUT; ++n) red[wv][n] = part[n];
    }
    __syncthreads();
    if (t < N_OUT) {
        float s = bias[t];
        #pragma unroll
        for (int w = 0; w < 8; ++w) s += red[w][t];
        out[b * N_OUT + t] = s;
    }
}

extern "C" void kernel_launch(void* const* d_in, const int* in_sizes, int n_in,
                              void* d_out, int out_size, void* d_ws, size_t ws_size,
                              hipStream_t stream) {
    const float* X    = (const float*)d_in[0];
    const float* W    = (const float*)d_in[1];
    const float* bias = (const float*)d_in[2];
    float* out = (float*)d_out;
    float* sig = (float*)d_ws;                 // NCHUNK*BATCH*SIG_DIM*4 ≈ 19.2 MB

    hipLaunchKernelGGL(sig_chunk_kernel, dim3(BATCH * NCHUNK), dim3(512), 0, stream, X, sig);
    hipLaunchKernelGGL(sig_combine_linear, dim3(BATCH), dim3(512), 0, stream, sig, W, bias, out);
}

// Round 15
// 42.805 us; speedup vs baseline: 1.8700x; 1.1142x over previous
//
#include <hip/hip_runtime.h>

#define BATCH 128
#define LEN 512
#define NCHUNK 8
#define CH_STEPS 64           // fixed: zero-padded dx makes step 511 identity
#define STEPS_TOTAL 511
#define SIG_DIM 4680          // 8 + 64 + 512 + 4096
#define N_OUT 10
#define OFF2 8
#define OFF3 72
#define OFF4 584
#define DXG_ELEMS (BATCH * LEN * 8)   // 524288 floats = 2 MB

// ---------------------------------------------------------------------------
// Kernel 0 (verified R3/R4): dx[b][s][0..7] = X[b][s+1]-X[b][s], 0 past end.
// ---------------------------------------------------------------------------
__global__ __launch_bounds__(512) void dx_kernel(const float* __restrict__ X,
                                                 float* __restrict__ dxg) {
    const int gid = blockIdx.x * 512 + threadIdx.x;   // one thread per (b, sg)
    const int b = gid >> 9, sg = gid & 511;
    float4 d0 = make_float4(0.f, 0.f, 0.f, 0.f);
    float4 d1 = d0;
    if (sg < STEPS_TOTAL) {
        const float4* xp = (const float4*)(X + ((size_t)b * LEN + sg) * 8);
        const float4 a0 = xp[0], a1 = xp[1], c0 = xp[2], c1 = xp[3];
        d0 = make_float4(c0.x - a0.x, c0.y - a0.y, c0.z - a0.z, c0.w - a0.w);
        d1 = make_float4(c1.x - a1.x, c1.y - a1.y, c1.z - a1.z, c1.w - a1.w);
    }
    float4* o = (float4*)(dxg + (size_t)gid * 8);     // [b][sg][8] contiguous
    o[0] = d0;
    o[1] = d1;
}

// ---------------------------------------------------------------------------
// Kernel 1: per-(batch, eighth) depth-4 signature, FAT-THREAD layout:
// one wave (64 thr) per chunk; thread t = (i,j) owns s3[k] (8 regs) and
// s4[k][l] (64 regs). Per step:
//   dx[0..7]: 2 uniform global_load_dwordx4 (no subs -- dx precomputed)
//   vi,vj   : 2 ds_read_b32 broadcast (conflict-free, R9-proven)
//   chain   : computed ONCE per (i,j) -- zero redundancy (was 8x)
//   cc/s3   : 16 FMA (dx_k = static register component)
//   s4      : 64 independent FMAs, all indices compile-time (stay in VGPRs)
// 1024 blocks x 64 threads = 4 waves/CU.
// ---------------------------------------------------------------------------
__global__ __launch_bounds__(64) void sig_chunk_kernel(const float* __restrict__ dxg,
                                                       float* __restrict__ sig) {
    const int wg = blockIdx.x;          // b * 8 + ch
    const int t = threadIdx.x;          // 0..63  = i*8 + j
    const int i = t >> 3, j = t & 7;

    __shared__ __align__(16) float dxs[CH_STEPS * 8];   // 2 KB, for vi/vj
    const float* __restrict__ g = dxg + (size_t)wg * (CH_STEPS * 8);
    ((float4*)dxs)[t]      = ((const float4*)g)[t];
    ((float4*)dxs)[t + 64] = ((const float4*)g)[t + 64];
    __syncthreads();

    float s1 = 0.f, s2 = 0.f;
    float s3[8] = {0.f, 0.f, 0.f, 0.f, 0.f, 0.f, 0.f, 0.f};
    float s4[8][8] = {};
    const float4* __restrict__ g4 = (const float4*)g;

    #pragma unroll 4
    for (int s = 0; s < CH_STEPS; ++s) {
        const float4 dA = g4[s * 2];        // uniform VMEM: dx[s][0..3]
        const float4 dB = g4[s * 2 + 1];    // dx[s][4..7]
        const float vi = dxs[s * 8 + i];    // LDS broadcast
        const float vj = dxs[s * 8 + j];    // LDS broadcast
        const float dv[8] = {dA.x, dA.y, dA.z, dA.w, dB.x, dB.y, dB.z, dB.w};

        const float t1 = s1 * vj;
        const float p  = vi * vj;
        // u = s2/2 + t1/6 + p/24 ; w = s2 + t1/2 + p/6   (pre-step state)
        const float u = fmaf(1.f / 24.f, p, fmaf(1.f / 6.f, t1, 0.5f * s2));
        const float w = fmaf(1.f / 6.f, p, fmaf(0.5f, t1, s2));

        float cc[8];
        #pragma unroll
        for (int k = 0; k < 8; ++k) {
            cc[k] = fmaf(dv[k], u, s3[k]);  // level-4 coefficient (per k)
            s3[k] = fmaf(dv[k], w, s3[k]);
        }
        #pragma unroll
        for (int k = 0; k < 8; ++k) {
            #pragma unroll
            for (int l = 0; l < 8; ++l)
                s4[k][l] = fmaf(cc[k], dv[l], s4[k][l]);
        }
        s2 = fmaf(0.5f, p, s2 + t1);
        s1 += vi;
    }

    float* __restrict__ o = sig + (size_t)wg * SIG_DIM;
    if (j == 0) o[i] = s1;                             // s1[i]
    o[OFF2 + t] = s2;                                  // s2[i*8+j]
    *(float4*)&o[OFF3 + t * 8]     = make_float4(s3[0], s3[1], s3[2], s3[3]);
    *(float4*)&o[OFF3 + t * 8 + 4] = make_float4(s3[4], s3[5], s3[6], s3[7]);
    #pragma unroll
    for (int k = 0; k < 8; ++k) {
        float* dst = &o[OFF4 + t * 64 + k * 8];
        *(float4*)dst       = make_float4(s4[k][0], s4[k][1], s4[k][2], s4[k][3]);
        *(float4*)(dst + 4) = make_float4(s4[k][4], s4[k][5], s4[k][6], s4[k][7]);
    }
}

// ---------------------------------------------------------------------------
// Chen combine: (A own-components in registers) ∘= (B cross-components via
// pointer -- global or LDS; addrspace resolved after inlining).
// ---------------------------------------------------------------------------
__device__ __forceinline__ void chen_combine(float& A1, float& A2, float& A3,
                                             float A4[8],
                                             const float* __restrict__ B,
                                             int i, int j, int k, int t) {
    const float B1i = B[i], B1j = B[j], B1k = B[k];
    const float4 b1a = *(const float4*)&B[0];
    const float4 b1b = *(const float4*)&B[4];
    const float B2ij = B[OFF2 + i * 8 + j];
    const float B2jk = B[OFF2 + j * 8 + k];
    const float4 b2a = *(const float4*)&B[OFF2 + k * 8];
    const float4 b2b = *(const float4*)&B[OFF2 + k * 8 + 4];
    const float B3ijk = B[OFF3 + t];
    const float4 b3a = *(const float4*)&B[OFF3 + (j * 8 + k) * 8];
    const float4 b3b = *(const float4*)&B[OFF3 + (j * 8 + k) * 8 + 4];
    const float4 b4a = *(const float4*)&B[OFF4 + t * 8];
    const float4 b4b = *(const float4*)&B[OFF4 + t * 8 + 4];

    // C4 = A4 + A3⊗B1 + A2⊗B2 + A1⊗B3 + B4   (old A1..A3)
    A4[0] += A3 * b1a.x + A2 * b2a.x + A1 * b3a.x + b4a.x;
    A4[1] += A3 * b1a.y + A2 * b2a.y + A1 * b3a.y + b4a.y;
    A4[2] += A3 * b1a.z + A2 * b2a.z + A1 * b3a.z + b4a.z;
    A4[3] += A3 * b1a.w + A2 * b2a.w + A1 * b3a.w + b4a.w;
    A4[4] += A3 * b1b.x + A2 * b2b.x + A1 * b3b.x + b4b.x;
    A4[5] += A3 * b1b.y + A2 * b2b.y + A1 * b3b.y + b4b.y;
    A4[6] += A3 * b1b.z + A2 * b2b.z + A1 * b3b.z + b4b.z;
    A4[7] += A3 * b1b.w + A2 * b2b.w + A1 * b3b.w + b4b.w;
    // C3 = A3 + A2⊗B1 + A1⊗B2 + B3
    A3 += A2 * B1k + A1 * B2jk + B3ijk;
    // C2 = A2 + A1⊗B1 + B2
    A2 += A1 * B1j + B2ij;
    // C1
    A1 += B1i;
}

__device__ __forceinline__ void load_own(const float* __restrict__ S,
                                         float& A1, float& A2, float& A3,
                                         float A4[8], int i, int j, int t) {
    A1 = S[i];
    A2 = S[OFF2 + i * 8 + j];
    A3 = S[OFF3 + t];
    const float4 a = *(const float4*)&S[OFF4 + t * 8];
    const float4 b = *(const float4*)&S[OFF4 + t * 8 + 4];
    A4[0] = a.x; A4[1] = a.y; A4[2] = a.z; A4[3] = a.w;
    A4[4] = b.x; A4[5] = b.y; A4[6] = b.z; A4[7] = b.w;
}

__device__ __forceinline__ void stage_lds(float* __restrict__ Bs,
                                          float A1, float A2, float A3,
                                          const float A4[8], int t) {
    if ((t & 63) == 0) Bs[t >> 6] = A1;
    if ((t & 7) == 0)  Bs[OFF2 + (t >> 3)] = A2;
    Bs[OFF3 + t] = A3;
    *(float4*)&Bs[OFF4 + t * 8]     = make_float4(A4[0], A4[1], A4[2], A4[3]);
    *(float4*)&Bs[OFF4 + t * 8 + 4] = make_float4(A4[4], A4[5], A4[6], A4[7]);
}

// ---------------------------------------------------------------------------
// Kernel 2 (verified R10/R12/R14): 3-level pairwise Chen-combine tree over 8
// chunk signatures + fused linear + block reduction. 128 blocks x 512 thr.
// ---------------------------------------------------------------------------
__global__ __launch_bounds__(512) void sig_combine_linear(const float* __restrict__ sig,
                                                          const float* __restrict__ W,
                                                          const float* __restrict__ bias,
                                                          float* __restrict__ out) {
    const int b = blockIdx.x;
    const int t = threadIdx.x;
    const int i = t >> 6, j = (t >> 3) & 7, k = t & 7;
    const float* __restrict__ S = sig + (size_t)b * NCHUNK * SIG_DIM;

    __shared__ __align__(16) float Bs0[SIG_DIM];
    __shared__ __align__(16) float Bs1[SIG_DIM];

    // level 1 (all from global, L2-resident):
    {
        float C1, C2, C3, C4[8];
        load_own(S + 2 * SIG_DIM, C1, C2, C3, C4, i, j, t);
        chen_combine(C1, C2, C3, C4, S + 3 * SIG_DIM, i, j, k, t);
        stage_lds(Bs0, C1, C2, C3, C4, t);
    }
    {
        float C1, C2, C3, C4[8];
        load_own(S + 6 * SIG_DIM, C1, C2, C3, C4, i, j, t);
        chen_combine(C1, C2, C3, C4, S + 7 * SIG_DIM, i, j, k, t);
        stage_lds(Bs1, C1, C2, C3, C4, t);
    }

    // C01 (running accumulator A in registers)
    float A1, A2, A3, A4[8];
    load_own(S, A1, A2, A3, A4, i, j, t);
    chen_combine(A1, A2, A3, A4, S + SIG_DIM, i, j, k, t);

    // C45 (registers)
    float D1, D2, D3, D4[8];
    load_own(S + 4 * SIG_DIM, D1, D2, D3, D4, i, j, t);
    chen_combine(D1, D2, D3, D4, S + 5 * SIG_DIM, i, j, k, t);

    __syncthreads();                      // LDS0 = C23, LDS1 = C67 ready

    // level 2: A = C0123, D = C4567
    chen_combine(A1, A2, A3, A4, Bs0, i, j, k, t);
    chen_combine(D1, D2, D3, D4, Bs1, i, j, k, t);

    __syncthreads();                      // everyone done reading LDS0
    stage_lds(Bs0, D1, D2, D3, D4, t);
    __syncthreads();                      // LDS0 = C4567 ready

    // level 3: A = full signature
    chen_combine(A1, A2, A3, A4, Bs0, i, j, k, t);

    // Fused linear: out[b][n] = sum_d sig[d] * W[n][d] + bias[n]
    float part[N_OUT];
    #pragma unroll
    for (int n = 0; n < N_OUT; ++n) {
        const float* __restrict__ Wn = W + (size_t)n * SIG_DIM;
        float p = A3 * Wn[OFF3 + t];
        const float4 w4a = *(const float4*)&Wn[OFF4 + t * 8];
        const float4 w4b = *(const float4*)&Wn[OFF4 + t * 8 + 4];
        p = fmaf(A4[0], w4a.x, p);
        p = fmaf(A4[1], w4a.y, p);
        p = fmaf(A4[2], w4a.z, p);
        p = fmaf(A4[3], w4a.w, p);
        p = fmaf(A4[4], w4b.x, p);
        p = fmaf(A4[5], w4b.y, p);
        p = fmaf(A4[6], w4b.z, p);
        p = fmaf(A4[7], w4b.w, p);
        if ((t & 7) == 0)  p = fmaf(A2, Wn[OFF2 + (t >> 3)], p);  // canonical s2 owner
        if ((t & 63) == 0) p = fmaf(A1, Wn[t >> 6], p);           // canonical s1 owner
        part[n] = p;
    }

    // wave reduce (64 lanes) then cross-wave via LDS
    #pragma unroll
    for (int n = 0; n < N_OUT; ++n) {
        #pragma unroll
        for (int off = 32; off > 0; off >>= 1)
            part[n] += __shfl_xor(part[n], off, 64);
    }
    __shared__ float red[8][N_OUT];
    const int wv = t >> 6, ln = t & 63;
    if (ln == 0) {
        #pragma unroll
        for (int n = 0; n < N_OUT; ++n) red[wv][n] = part[n];
    }
    __syncthreads();
    if (t < N_OUT) {
        float s = bias[t];
        #pragma unroll
        for (int w = 0; w < 8; ++w) s += red[w][t];
        out[b * N_OUT + t] = s;
    }
}

extern "C" void kernel_launch(void* const* d_in, const int* in_sizes, int n_in,
                              void* d_out, int out_size, void* d_ws, size_t ws_size,
                              hipStream_t stream) {
    const float* X    = (const float*)d_in[0];
    const float* W    = (const float*)d_in[1];
    const float* bias = (const float*)d_in[2];
    float* out = (float*)d_out;
    float* dxg = (float*)d_ws;                 // 2 MB
    float* sig = (float*)d_ws + DXG_ELEMS;     // NCHUNK*BATCH*SIG_DIM*4 ≈ 19.2 MB

    hipLaunchKernelGGL(dx_kernel, dim3(BATCH * LEN / 512), dim3(512), 0, stream, X, dxg);
    hipLaunchKernelGGL(sig_chunk_kernel, dim3(BATCH * NCHUNK), dim3(64), 0, stream, dxg, sig);
    hipLaunchKernelGGL(sig_combine_linear, dim3(BATCH), dim3(512), 0, stream, sig, W, bias, out);
}

// Round 16
// 34.087 us; speedup vs baseline: 2.3483x; 1.2557x over previous
//
#include <hip/hip_runtime.h>

#define BATCH 128
#define LEN 512
#define N_OUT 10
#define SIG_DIM 4680
// canonical (thin) sig offsets -- used for W indexing only
#define OFF2W 8
#define OFF3W 72
#define OFF4W 584
// FATPAD LDS signature buffer: B1[8] | B2[64] | B3[64x9 pad] | B4[64x65 pad]
#define B2OFF 8
#define B3OFF 72
#define B4OFF 648
#define BUFSZ 4808

typedef float v4f __attribute__((ext_vector_type(4)));

// stage a fat-layout signature (thread lane=(i,j) owns s2, s3[k], s4[k][l])
// into a FATPAD LDS buffer. Strides 9/65 give <=2-way bank conflicts.
__device__ __forceinline__ void stage_fat(float* __restrict__ buf,
                                          float s1, float s2,
                                          const float s3[8], const float s4[8][8],
                                          int lane) {
    if ((lane & 7) == 0) buf[lane >> 3] = s1;          // B1[i] (j==0 canonical)
    buf[B2OFF + lane] = s2;                            // B2[ij]
    #pragma unroll
    for (int k = 0; k < 8; ++k) buf[B3OFF + lane * 9 + k] = s3[k];
    #pragma unroll
    for (int k = 0; k < 8; ++k) {
        #pragma unroll
        for (int l = 0; l < 8; ++l)
            buf[B4OFF + lane * 65 + k * 8 + l] = s4[k][l];
    }
}

// Chen combine in fat layout: A (regs, earlier chunk) ∘= B (FATPAD LDS).
// Same math as the verified thin chen_combine, k-vectorized per thread.
__device__ __forceinline__ void combine_fat(float& A1, float& A2,
                                            float A3[8], float A4[8][8],
                                            const float* __restrict__ buf,
                                            int i, int j, int lane) {
    float B1[8];
    #pragma unroll
    for (int l = 0; l < 8; ++l) B1[l] = buf[l];
    // C4 = A4 + A3⊗B1 + A2⊗B2 + A1⊗B3 + B4   (old A1..A3)
    #pragma unroll
    for (int k = 0; k < 8; ++k) {
        #pragma unroll
        for (int l = 0; l < 8; ++l) {
            A4[k][l] += A3[k] * B1[l]
                      + A2 * buf[B2OFF + k * 8 + l]
                      + A1 * buf[B3OFF + (j * 8 + k) * 9 + l]
                      + buf[B4OFF + lane * 65 + k * 8 + l];
        }
    }
    // C3 = A3 + A2⊗B1 + A1⊗B2 + B3
    #pragma unroll
    for (int k = 0; k < 8; ++k) {
        A3[k] += A2 * B1[k]
               + A1 * buf[B2OFF + j * 8 + k]
               + buf[B3OFF + lane * 9 + k];
    }
    // C2 = A2 + A1⊗B1 + B2
    A2 += A1 * B1[j] + buf[B2OFF + lane];
    // C1
    A1 += B1[i];
}

// ---------------------------------------------------------------------------
// Single fused kernel: one block per batch element (128 x 512).
// Phase 0: dx -> LDS (16 KB).  Phase 1: 8 waves scan 8 chunks (fat layout).
// Phase 2: in-block 3-level Chen tree via 4 FATPAD LDS buffers.
// Phase 3: fused linear + block reduction.  No workspace, one dispatch.
// ---------------------------------------------------------------------------
__global__ __launch_bounds__(512) void sig_fused_kernel(const float* __restrict__ X,
                                                        const float* __restrict__ W,
                                                        const float* __restrict__ bias,
                                                        float* __restrict__ out) {
    const int b = blockIdx.x;
    const int t = threadIdx.x;
    const int w = t >> 6;           // wave id == chunk id
    const int lane = t & 63;        // (i,j)
    const int i = lane >> 3, j = lane & 7;

    __shared__ __align__(16) float lds[4 * BUFSZ];     // 75.1 KB
    __shared__ float red[8][N_OUT];

    // ---- Phase 0: dx[s][c] = X[s+1][c]-X[s][c] into lds[0..4095], row 511 = 0
    {
        const float2* __restrict__ X2 = (const float2*)(X + (size_t)b * LEN * 8);
        float2* __restrict__ d2 = (float2*)lds;
        #pragma unroll
        for (int p = 0; p < 4; ++p) {
            const int q = t + p * 512;                 // float2 index 0..2047
            const int s = q >> 2;
            float2 r = make_float2(0.f, 0.f);
            if (s < LEN - 1) {
                const float2 a = X2[q], c = X2[q + 4];
                r = make_float2(c.x - a.x, c.y - a.y);
            }
            d2[q] = r;
        }
    }
    __syncthreads();

    // ---- Phase 1: fat scan; wave w scans chunk w (64 steps; wave 7: 63)
    float s1 = 0.f, s2 = 0.f;
    float s3[8] = {};
    float s4[8][8] = {};
    {
        const int s0 = w * 64;
        const int nst = (w == 7) ? 63 : 64;            // avoid X[512] OOB
        const v4f* __restrict__ Xv = (const v4f*)(X + (size_t)b * LEN * 8);
        v4f pA = Xv[s0 * 2], pB = Xv[s0 * 2 + 1];
        const v4f* __restrict__ Xn = Xv + (s0 + 1) * 2;
        const float* __restrict__ dxL = lds + s0 * 8;
        #pragma unroll 4
        for (int s = 0; s < nst; ++s) {
            const v4f cA = Xn[s * 2], cB = Xn[s * 2 + 1];   // uniform VMEM
            const v4f dA = cA - pA, dB = cB - pB;
            pA = cA; pB = cB;
            const float vi = dxL[s * 8 + i];           // LDS broadcast (8 banks)
            const float vj = dxL[s * 8 + j];
            const float dv[8] = {dA.x, dA.y, dA.z, dA.w, dB.x, dB.y, dB.z, dB.w};

            const float t1 = s1 * vj;
            const float p  = vi * vj;
            const float u  = fmaf(1.f / 24.f, p, fmaf(1.f / 6.f, t1, 0.5f * s2));
            const float ww = fmaf(1.f / 6.f, p, fmaf(0.5f, t1, s2));
            float cc[8];
            #pragma unroll
            for (int k = 0; k < 8; ++k) {
                cc[k] = fmaf(dv[k], u, s3[k]);
                s3[k] = fmaf(dv[k], ww, s3[k]);
            }
            #pragma unroll
            for (int k = 0; k < 8; ++k) {
                #pragma unroll
                for (int l = 0; l < 8; ++l)
                    s4[k][l] = fmaf(cc[k], dv[l], s4[k][l]);
            }
            s2 = fmaf(0.5f, p, s2 + t1);
            s1 += vi;
        }
    }
    __syncthreads();            // dx region dead; lds becomes 4 sig buffers

    float* __restrict__ buf0 = lds;
    float* __restrict__ buf1 = lds + BUFSZ;
    float* __restrict__ buf2 = lds + 2 * BUFSZ;
    float* __restrict__ buf3 = lds + 3 * BUFSZ;

    // ---- Phase 2: pairwise Chen tree (chunks ascending; A = earlier)
    // L1 stage: odd chunks
    if (w == 1) stage_fat(buf0, s1, s2, s3, s4, lane);
    if (w == 3) stage_fat(buf1, s1, s2, s3, s4, lane);
    if (w == 5) stage_fat(buf2, s1, s2, s3, s4, lane);
    if (w == 7) stage_fat(buf3, s1, s2, s3, s4, lane);
    __syncthreads();
    // L1 combine: C01, C23, C45, C67
    if (w == 0) combine_fat(s1, s2, s3, s4, buf0, i, j, lane);
    if (w == 2) combine_fat(s1, s2, s3, s4, buf1, i, j, lane);
    if (w == 4) combine_fat(s1, s2, s3, s4, buf2, i, j, lane);
    if (w == 6) combine_fat(s1, s2, s3, s4, buf3, i, j, lane);
    __syncthreads();
    // L2 stage: C23 -> buf0, C67 -> buf1
    if (w == 2) stage_fat(buf0, s1, s2, s3, s4, lane);
    if (w == 6) stage_fat(buf1, s1, s2, s3, s4, lane);
    __syncthreads();
    // L2 combine: C0123 (wave 0), C4567 (wave 4)
    if (w == 0) combine_fat(s1, s2, s3, s4, buf0, i, j, lane);
    if (w == 4) combine_fat(s1, s2, s3, s4, buf1, i, j, lane);
    __syncthreads();
    // L3 stage: C4567 -> buf0
    if (w == 4) stage_fat(buf0, s1, s2, s3, s4, lane);
    __syncthreads();
    // L3 combine: full signature in wave 0 regs
    if (w == 0) combine_fat(s1, s2, s3, s4, buf0, i, j, lane);
    __syncthreads();
    // final stage: full signature -> buf0 (FATPAD) for all waves to read
    if (w == 0) stage_fat(buf0, s1, s2, s3, s4, lane);
    __syncthreads();

    // ---- Phase 3: fused linear (verified epilogue; A-values from buf0)
    const int ij = t >> 3, kk = t & 7;
    const float myA3 = buf0[B3OFF + ij * 9 + kk];
    float myA4[8];
    #pragma unroll
    for (int l = 0; l < 8; ++l) myA4[l] = buf0[B4OFF + ij * 65 + kk * 8 + l];
    const float myA2 = buf0[B2OFF + ij];    // canonical owner: kk == 0
    const float myA1 = buf0[t >> 6];        // canonical owner: (t&63) == 0

    float part[N_OUT];
    #pragma unroll
    for (int n = 0; n < N_OUT; ++n) {
        const float* __restrict__ Wn = W + (size_t)n * SIG_DIM;
        float p = myA3 * Wn[OFF3W + t];
        const float4 w4a = *(const float4*)&Wn[OFF4W + t * 8];
        const float4 w4b = *(const float4*)&Wn[OFF4W + t * 8 + 4];
        p = fmaf(myA4[0], w4a.x, p);
        p = fmaf(myA4[1], w4a.y, p);
        p = fmaf(myA4[2], w4a.z, p);
        p = fmaf(myA4[3], w4a.w, p);
        p = fmaf(myA4[4], w4b.x, p);
        p = fmaf(myA4[5], w4b.y, p);
        p = fmaf(myA4[6], w4b.z, p);
        p = fmaf(myA4[7], w4b.w, p);
        if ((t & 7) == 0)  p = fmaf(myA2, Wn[OFF2W + (t >> 3)], p);
        if ((t & 63) == 0) p = fmaf(myA1, Wn[t >> 6], p);
        part[n] = p;
    }

    // wave reduce (64 lanes) then cross-wave via LDS
    #pragma unroll
    for (int n = 0; n < N_OUT; ++n) {
        #pragma unroll
        for (int off = 32; off > 0; off >>= 1)
            part[n] += __shfl_xor(part[n], off, 64);
    }
    if (lane == 0) {
        #pragma unroll
        for (int n = 0; n < N_OUT; ++n) red[w][n] = part[n];
    }
    __syncthreads();
    if (t < N_OUT) {
        float s = bias[t];
        #pragma unroll
        for (int q = 0; q < 8; ++q) s += red[q][t];
        out[b * N_OUT + t] = s;
    }
}

extern "C" void kernel_launch(void* const* d_in, const int* in_sizes, int n_in,
                              void* d_out, int out_size, void* d_ws, size_t ws_size,
                              hipStream_t stream) {
    const float* X    = (const float*)d_in[0];
    const float* W    = (const float*)d_in[1];
    const float* bias = (const float*)d_in[2];
    float* out = (float*)d_out;
    (void)d_ws; (void)ws_size;

    hipLaunchKernelGGL(sig_fused_kernel, dim3(BATCH), dim3(512), 0, stream,
                       X, W, bias, out);
}